// Round 10
// baseline (123.997 us; speedup 1.0000x reference)
//
#include <hip/hip_runtime.h>

// 1-NN (squared-L2 argmin over 500000x256 f32 keys) + dot(values[idx], query).
// Memory-bound: 512 MB of keys stream once; floor ~= 512MB / 6.29 TB/s = 81 us.
// R10 = R9 (87.0 us best) with ONE change: GRID 1024->512 (2 blocks/CU,
// 8 waves/CU) -> collective sliding window tightens 8 MB -> 4 MB. Terminal
// probe of the window-size sweep (the only lever that has paid: 512MB chunked
// 96.8 -> 16MB 93.4 -> 8MB 87.0). Latency margin: 16 outstanding 1KB loads/CU
// vs ~8.3 needed -> ~2x headroom.
// Anti-lessons (measured): NT loads ~5x slower streams (R2); per-block
// ordered atomics/fences +91 us tail (R6); ILP depth 2/4/prefetch all
// neutral (R4/R8); 1-wave finish neutral (R7).

#define D 256
#define D4 (D / 4)            // 64 float4 per row == one wave-wide 1 KB load
#define BLOCK 256
#define GRID 512              // 2 blocks/CU, 8 waves/CU
#define WPB (BLOCK / 64)
#define NWAV (GRID * WPB)     // 2048 waves -> 4 MB lockstep window

// Monotonic float->uint map (inputs are finite gaussians, no NaN).
__device__ __forceinline__ unsigned int fkey(float f) {
    unsigned int u = __float_as_uint(f);
    return (u & 0x80000000u) ? ~u : (u | 0x80000000u);
}

__device__ __forceinline__ float rowpart(float4 a, float4 qm2) {
    return a.x * (a.x + qm2.x) + a.y * (a.y + qm2.y)
         + a.z * (a.z + qm2.z) + a.w * (a.w + qm2.w);
}

__global__ __launch_bounds__(BLOCK) void nn_argmin_kernel(
    const float* __restrict__ query,
    const float* __restrict__ keys,
    unsigned long long* __restrict__ blockBest,  // d_ws, GRID entries
    int N)
{
    const int lane  = threadIdx.x & 63;
    const int wib   = threadIdx.x >> 6;
    const int gwave = blockIdx.x * WPB + wib;

    const float4 q = reinterpret_cast<const float4*>(query)[lane];
    const float4 qm2 = make_float4(-2.f * q.x, -2.f * q.y, -2.f * q.z, -2.f * q.w);

    unsigned long long myBest = 0xFFFFFFFFFFFFFFFFull;  // smaller == better

    const float4* __restrict__ k4 = reinterpret_cast<const float4*>(keys);

    // Strided sweep: at any iteration the 2048 waves collectively read one
    // contiguous 4 MB window sliding through keys.
    for (int r = gwave * 2; r + 1 < N; r += 2 * NWAV) {
        float4 a = k4[(size_t)(r + 0) * D4 + lane];
        float4 b = k4[(size_t)(r + 1) * D4 + lane];
        float pa = rowpart(a, qm2);
        float pb = rowpart(b, qm2);
        #pragma unroll
        for (int off = 32; off; off >>= 1) {
            pa += __shfl_down(pa, off, 64);
            pb += __shfl_down(pb, off, 64);
        }
        if (lane == 0) {
            unsigned long long ka = ((unsigned long long)fkey(pa) << 32) | (unsigned int)(r + 0);
            unsigned long long kb = ((unsigned long long)fkey(pb) << 32) | (unsigned int)(r + 1);
            ka = min(ka, kb);
            if (ka < myBest) myBest = ka;
        }
    }
    if (N & 1) {   // dead for N=500000, kept for safety
        int rl = N - 1;
        if (((rl >> 1) % NWAV) == gwave) {
            float4 a = k4[(size_t)rl * D4 + lane];
            float pa = rowpart(a, qm2);
            #pragma unroll
            for (int off = 32; off; off >>= 1) pa += __shfl_down(pa, off, 64);
            if (lane == 0) {
                unsigned long long ka = ((unsigned long long)fkey(pa) << 32) | (unsigned int)rl;
                if (ka < myBest) myBest = ka;
            }
        }
    }

    // Block reduction in LDS, then ONE plain store per block (no atomics,
    // every slot overwritten every call -> no init dispatch needed).
    __shared__ unsigned long long s_best[WPB];
    if (lane == 0) s_best[wib] = myBest;
    __syncthreads();
    if (threadIdx.x == 0) {
        unsigned long long m = s_best[0];
        #pragma unroll
        for (int i = 1; i < WPB; ++i) m = min(m, s_best[i]);
        blockBest[blockIdx.x] = m;
    }
}

__global__ __launch_bounds__(BLOCK) void nn_finish_kernel(
    const float* __restrict__ query,
    const float* __restrict__ values,
    const unsigned long long* __restrict__ blockBest,
    float* __restrict__ out)
{
    const int tid  = threadIdx.x;
    const int lane = tid & 63;
    const int wib  = tid >> 6;

    // Min-reduce GRID packed entries (4 KB), coalesced.
    unsigned long long m = 0xFFFFFFFFFFFFFFFFull;
    #pragma unroll
    for (int i = 0; i < GRID / BLOCK; ++i)
        m = min(m, blockBest[i * BLOCK + tid]);
    #pragma unroll
    for (int off = 32; off; off >>= 1)
        m = min(m, __shfl_down(m, off, 64));

    __shared__ unsigned long long s_best[BLOCK / 64];
    __shared__ int s_idx;
    if (lane == 0) s_best[wib] = m;
    __syncthreads();
    if (tid == 0) {
        unsigned long long mm = s_best[0];
        #pragma unroll
        for (int i = 1; i < BLOCK / 64; ++i) mm = min(mm, s_best[i]);
        s_idx = (int)(mm & 0xFFFFFFFFull);
    }
    __syncthreads();

    if (tid < 64) {
        const float4 v = reinterpret_cast<const float4*>(values)[(size_t)s_idx * D4 + lane];
        const float4 q = reinterpret_cast<const float4*>(query)[lane];
        float d = v.x * q.x + v.y * q.y + v.z * q.z + v.w * q.w;
        #pragma unroll
        for (int off = 32; off; off >>= 1) d += __shfl_down(d, off, 64);
        if (lane == 0) out[0] = d;
    }
}

extern "C" void kernel_launch(void* const* d_in, const int* in_sizes, int n_in,
                              void* d_out, int out_size, void* d_ws, size_t ws_size,
                              hipStream_t stream) {
    const float* query  = (const float*)d_in[0];
    const float* keys   = (const float*)d_in[1];
    const float* values = (const float*)d_in[2];
    const int N = in_sizes[1] / D;

    unsigned long long* blockBest = (unsigned long long*)d_ws;  // 4 KB used

    nn_argmin_kernel<<<GRID, BLOCK, 0, stream>>>(query, keys, blockBest, N);
    nn_finish_kernel<<<1, BLOCK, 0, stream>>>(query, values, blockBest,
                                              (float*)d_out);
}

// Round 11
// 86.929 us; speedup vs baseline: 1.4264x; 1.4264x over previous
//
#include <hip/hip_runtime.h>

// 1-NN (squared-L2 argmin over 500000x256 f32 keys) + dot(values[idx], query).
// Memory-bound: 512 MB of keys stream once; floor ~= 512MB / 6.29 TB/s = 81 us.
// R11 = exact revert to R9 (measured best, 87.0 us): strided sliding-window,
// GRID=1024 (4 blocks/CU, 16 waves/CU, 8 MB lockstep window), 2 rows/iter,
// plain loads, plain per-block store, 256-thread finish kernel.
//
// Window-size sweep (measured): 512MB chunked 96.8 | 16MB 93.4 | 8MB 87.0 |
// 4MB 124.0 (occupancy cliff: 8 waves/CU can't cover HBM latency).
// Anti-lessons (measured): NT loads ~5x slower streams (R2); per-block
// ordered atomics/fences +91 us serialized tail (R6); ILP depth 2/4/prefetch
// all neutral (R4/R8); 1-wave finish neutral (R7).
// argmin at ~6.17 TB/s ~= 98% of measured read ceiling -> roofline.

#define D 256
#define D4 (D / 4)            // 64 float4 per row == one wave-wide 1 KB load
#define BLOCK 256
#define GRID 1024             // 4 blocks/CU, 16 waves/CU
#define WPB (BLOCK / 64)
#define NWAV (GRID * WPB)     // 4096 waves -> 8 MB lockstep window

// Monotonic float->uint map (inputs are finite gaussians, no NaN).
__device__ __forceinline__ unsigned int fkey(float f) {
    unsigned int u = __float_as_uint(f);
    return (u & 0x80000000u) ? ~u : (u | 0x80000000u);
}

__device__ __forceinline__ float rowpart(float4 a, float4 qm2) {
    return a.x * (a.x + qm2.x) + a.y * (a.y + qm2.y)
         + a.z * (a.z + qm2.z) + a.w * (a.w + qm2.w);
}

__global__ __launch_bounds__(BLOCK) void nn_argmin_kernel(
    const float* __restrict__ query,
    const float* __restrict__ keys,
    unsigned long long* __restrict__ blockBest,  // d_ws, GRID entries
    int N)
{
    const int lane  = threadIdx.x & 63;
    const int wib   = threadIdx.x >> 6;
    const int gwave = blockIdx.x * WPB + wib;

    const float4 q = reinterpret_cast<const float4*>(query)[lane];
    const float4 qm2 = make_float4(-2.f * q.x, -2.f * q.y, -2.f * q.z, -2.f * q.w);

    unsigned long long myBest = 0xFFFFFFFFFFFFFFFFull;  // smaller == better

    const float4* __restrict__ k4 = reinterpret_cast<const float4*>(keys);

    // Strided sweep: at any iteration the 4096 waves collectively read one
    // contiguous 8 MB window sliding through keys.
    for (int r = gwave * 2; r + 1 < N; r += 2 * NWAV) {
        float4 a = k4[(size_t)(r + 0) * D4 + lane];
        float4 b = k4[(size_t)(r + 1) * D4 + lane];
        float pa = rowpart(a, qm2);
        float pb = rowpart(b, qm2);
        #pragma unroll
        for (int off = 32; off; off >>= 1) {
            pa += __shfl_down(pa, off, 64);
            pb += __shfl_down(pb, off, 64);
        }
        if (lane == 0) {
            unsigned long long ka = ((unsigned long long)fkey(pa) << 32) | (unsigned int)(r + 0);
            unsigned long long kb = ((unsigned long long)fkey(pb) << 32) | (unsigned int)(r + 1);
            ka = min(ka, kb);
            if (ka < myBest) myBest = ka;
        }
    }
    if (N & 1) {   // dead for N=500000, kept for safety
        int rl = N - 1;
        if (((rl >> 1) % NWAV) == gwave) {
            float4 a = k4[(size_t)rl * D4 + lane];
            float pa = rowpart(a, qm2);
            #pragma unroll
            for (int off = 32; off; off >>= 1) pa += __shfl_down(pa, off, 64);
            if (lane == 0) {
                unsigned long long ka = ((unsigned long long)fkey(pa) << 32) | (unsigned int)rl;
                if (ka < myBest) myBest = ka;
            }
        }
    }

    // Block reduction in LDS, then ONE plain store per block (no atomics,
    // every slot overwritten every call -> no init dispatch needed).
    __shared__ unsigned long long s_best[WPB];
    if (lane == 0) s_best[wib] = myBest;
    __syncthreads();
    if (threadIdx.x == 0) {
        unsigned long long m = s_best[0];
        #pragma unroll
        for (int i = 1; i < WPB; ++i) m = min(m, s_best[i]);
        blockBest[blockIdx.x] = m;
    }
}

__global__ __launch_bounds__(BLOCK) void nn_finish_kernel(
    const float* __restrict__ query,
    const float* __restrict__ values,
    const unsigned long long* __restrict__ blockBest,
    float* __restrict__ out)
{
    const int tid  = threadIdx.x;
    const int lane = tid & 63;
    const int wib  = tid >> 6;

    // Min-reduce GRID packed entries (8 KB), coalesced.
    unsigned long long m = 0xFFFFFFFFFFFFFFFFull;
    #pragma unroll
    for (int i = 0; i < GRID / BLOCK; ++i)
        m = min(m, blockBest[i * BLOCK + tid]);
    #pragma unroll
    for (int off = 32; off; off >>= 1)
        m = min(m, __shfl_down(m, off, 64));

    __shared__ unsigned long long s_best[BLOCK / 64];
    __shared__ int s_idx;
    if (lane == 0) s_best[wib] = m;
    __syncthreads();
    if (tid == 0) {
        unsigned long long mm = s_best[0];
        #pragma unroll
        for (int i = 1; i < BLOCK / 64; ++i) mm = min(mm, s_best[i]);
        s_idx = (int)(mm & 0xFFFFFFFFull);
    }
    __syncthreads();

    if (tid < 64) {
        const float4 v = reinterpret_cast<const float4*>(values)[(size_t)s_idx * D4 + lane];
        const float4 q = reinterpret_cast<const float4*>(query)[lane];
        float d = v.x * q.x + v.y * q.y + v.z * q.z + v.w * q.w;
        #pragma unroll
        for (int off = 32; off; off >>= 1) d += __shfl_down(d, off, 64);
        if (lane == 0) out[0] = d;
    }
}

extern "C" void kernel_launch(void* const* d_in, const int* in_sizes, int n_in,
                              void* d_out, int out_size, void* d_ws, size_t ws_size,
                              hipStream_t stream) {
    const float* query  = (const float*)d_in[0];
    const float* keys   = (const float*)d_in[1];
    const float* values = (const float*)d_in[2];
    const int N = in_sizes[1] / D;

    unsigned long long* blockBest = (unsigned long long*)d_ws;  // 8 KB used

    nn_argmin_kernel<<<GRID, BLOCK, 0, stream>>>(query, keys, blockBest, N);
    nn_finish_kernel<<<1, BLOCK, 0, stream>>>(query, values, blockBest,
                                              (float*)d_out);
}